// Round 1
// baseline (272.430 us; speedup 1.0000x reference)
//
#include <hip/hip_runtime.h>
#include <math.h>

#define BB 16
#define TD 1024
#define HD 512
#define UD 600
#define AD 80
#define KG 10
#define PC 30      // 3*K
#define PP 32      // padded param cols

#define LOG2E 1.4426950408889634f

#if __has_builtin(__builtin_amdgcn_exp2f)
#define EXP2F(x) __builtin_amdgcn_exp2f(x)
#else
#define EXP2F(x) exp2f(x)
#endif

// -------- kernel 1: transpose W [512][30] -> wT [32][512], zero-padded cols
__global__ void k_transpose(const float* __restrict__ W, float* __restrict__ wT) {
    int gid = blockIdx.x * 256 + threadIdx.x;   // 0 .. 32*512-1
    if (gid >= PP * HD) return;
    int c = gid >> 9;        // col of W  (row of wT)
    int h = gid & 511;
    wT[gid] = (c < PC) ? W[h * PC + c] : 0.f;
}

// -------- kernel 2: params GEMM + exp + transform
// ep[row][32]: cols 0..9  a  = exp(p)
//              cols 10..19 nb = -exp(p)*log2(e)
//              cols 20..29 k  = exp(p)
__global__ __launch_bounds__(256) void k_params(const float* __restrict__ x,
                                                const float* __restrict__ wT,
                                                const float* __restrict__ bias,
                                                float* __restrict__ ep) {
    int tid = threadIdx.x;
    int ty = tid >> 3;          // 0..31  row within tile
    int tx = tid & 7;           // 0..7   col group (4 cols)
    long row = (long)blockIdx.x * 32 + ty;
    const float* xr = x + row * HD;
    int c0 = tx * 4;
    const float* w0 = wT + (long)(c0 + 0) * HD;
    const float* w1 = wT + (long)(c0 + 1) * HD;
    const float* w2 = wT + (long)(c0 + 2) * HD;
    const float* w3 = wT + (long)(c0 + 3) * HD;
    float a0 = 0.f, a1 = 0.f, a2 = 0.f, a3 = 0.f;
    for (int h = 0; h < HD; h += 4) {
        float4 xv  = *(const float4*)(xr + h);
        float4 wv0 = *(const float4*)(w0 + h);
        float4 wv1 = *(const float4*)(w1 + h);
        float4 wv2 = *(const float4*)(w2 + h);
        float4 wv3 = *(const float4*)(w3 + h);
        a0 += xv.x*wv0.x + xv.y*wv0.y + xv.z*wv0.z + xv.w*wv0.w;
        a1 += xv.x*wv1.x + xv.y*wv1.y + xv.z*wv1.z + xv.w*wv1.w;
        a2 += xv.x*wv2.x + xv.y*wv2.y + xv.z*wv2.z + xv.w*wv2.w;
        a3 += xv.x*wv3.x + xv.y*wv3.y + xv.z*wv3.z + xv.w*wv3.w;
    }
    float accs[4] = {a0, a1, a2, a3};
    #pragma unroll
    for (int j = 0; j < 4; j++) {
        int c = c0 + j;
        float val = 0.f;
        if (c < PC) {
            float e = __expf(accs[j] + bias[c]);
            val = (c >= 10 && c < 20) ? (-e * LOG2E) : e;
        }
        ep[row * PP + c] = val;
    }
}

// -------- kernel 3: fused gaussian window + btu,bua->bta einsum
#define TT 32     // t-tile per block
#define UC 40     // u chunk
#define NCHUNK 15 // 600/40
#define NTHR 320  // 5 waves

__global__ __launch_bounds__(NTHR) void k_main(const float* __restrict__ ep,
                                               const float* __restrict__ cs,
                                               float* __restrict__ out) {
    __shared__ float params_l[TT * 33];   // pitch 33: kill bank conflicts
    __shared__ float cs_l[UC * AD];       // [u][a] pitch 80
    __shared__ float phi_l[UC * 33];      // [u][t] pitch 33

    int tid = threadIdx.x;
    int b = blockIdx.y;
    int t0 = blockIdx.x * TT;
    long r0 = (long)b * TD + t0;

    // ---- stage params for this block's 32 t's
    for (int idx = tid; idx < TT * PP; idx += NTHR) {
        int tt_ = idx >> 5, j = idx & 31;
        params_l[tt_ * 33 + j] = ep[r0 * PP + idx];
    }
    __syncthreads();

    // ---- phi role: thread owns t = tt (tid&31), u-slice sub (tid>>5, 0..9)
    int tt = tid & 31;
    int sub = tid >> 5;
    float pa[KG], pnb[KG], pk[KG];
    #pragma unroll
    for (int q = 0; q < KG; q++) {
        pa[q]  = params_l[tt * 33 + q];
        pnb[q] = params_l[tt * 33 + 10 + q];
        pk[q]  = params_l[tt * 33 + 20 + q];
    }

    // ---- einsum role: thread owns t-pair ty*2, a-quad tx*4
    int tx = tid % 20;   // 0..19
    int ty = tid / 20;   // 0..15
    float4 acc0 = {0.f, 0.f, 0.f, 0.f};
    float4 acc1 = {0.f, 0.f, 0.f, 0.f};

    const float* csb = cs + (long)b * UD * AD;

    for (int ch = 0; ch < NCHUNK; ch++) {
        int u0 = ch * UC;
        __syncthreads();   // protect cs_l/phi_l from previous einsum readers

        // stage char_seq chunk: contiguous UC*AD floats, fully coalesced
        for (int idx = tid; idx < UC * AD; idx += NTHR) {
            cs_l[idx] = csb[u0 * AD + idx];
        }

        // compute phi for my t, my 4 u's
        #pragma unroll
        for (int i = 0; i < 4; i++) {
            int uu = sub * 4 + i;
            float uf = (float)(u0 + uu);
            float s = 0.f;
            #pragma unroll
            for (int q = 0; q < KG; q++) {
                float d = uf - pk[q];
                s += pa[q] * EXP2F(pnb[q] * d * d);
            }
            phi_l[uu * 33 + tt] = s;
        }
        __syncthreads();

        // einsum accumulate: out[t][a] += phi[t][u] * cs[u][a]
        #pragma unroll 8
        for (int uu = 0; uu < UC; uu++) {
            float p0 = phi_l[uu * 33 + ty * 2];
            float p1 = phi_l[uu * 33 + ty * 2 + 1];
            float4 c4 = *(const float4*)&cs_l[uu * AD + tx * 4];
            acc0.x += p0 * c4.x; acc0.y += p0 * c4.y;
            acc0.z += p0 * c4.z; acc0.w += p0 * c4.w;
            acc1.x += p1 * c4.x; acc1.y += p1 * c4.y;
            acc1.z += p1 * c4.z; acc1.w += p1 * c4.w;
        }
    }

    // ---- store 2 t-rows x 4 a's
    long t = r0 + ty * 2;
    *(float4*)(out + t * AD + tx * 4) = acc0;
    *(float4*)(out + (t + 1) * AD + tx * 4) = acc1;
}

extern "C" void kernel_launch(void* const* d_in, const int* in_sizes, int n_in,
                              void* d_out, int out_size, void* d_ws, size_t ws_size,
                              hipStream_t stream) {
    const float* lstm = (const float*)d_in[0];   // [16,1024,512]
    const float* cs   = (const float*)d_in[1];   // [16,600,80]
    const float* W    = (const float*)d_in[2];   // [512,30]
    const float* bias = (const float*)d_in[3];   // [30]
    float* out = (float*)d_out;                  // [16,1024,80]

    float* wT = (float*)d_ws;                    // 32*512 floats
    float* ep = (float*)d_ws + PP * HD;          // 16384*32 floats

    k_transpose<<<(PP * HD + 255) / 256, 256, 0, stream>>>(W, wT);
    k_params<<<(BB * TD) / 32, 256, 0, stream>>>(lstm, wT, bias, ep);
    dim3 grid(TD / TT, BB);
    k_main<<<grid, NTHR, 0, stream>>>(ep, cs, out);
}

// Round 2
// 170.773 us; speedup vs baseline: 1.5953x; 1.5953x over previous
//
#include <hip/hip_runtime.h>
#include <math.h>

#define BB 16
#define TD 1024
#define HD 512
#define UD 600
#define AD 80
#define KG 10
#define PC 30      // 3*K
#define PP 32      // padded param cols

#define LOG2E 1.4426950408889634f

#if __has_builtin(__builtin_amdgcn_exp2f)
#define EXP2F(x) __builtin_amdgcn_exp2f(x)
#else
#define EXP2F(x) exp2f(x)
#endif

// -------- kernel 1: params GEMM + exp + transform
// [16384 x 512] @ [512 x 30]. Block = 256 thr = 4 waves; wave w owns h-slice
// [128w, 128w+128), lane owns one of 64 rows. W index is wave-uniform ->
// scalar loads (s_load) via readfirstlane; x read exactly once, lane-gathered.
// ep[row][32]: cols 0..9  a  = exp(p)
//              cols 10..19 nb = -exp(p)*log2(e)
//              cols 20..29 k  = exp(p)
#define ROWS_PB 64
#define SPLITH 4
#define HSL (HD / SPLITH)   // 128

__global__ __launch_bounds__(256) void k_params(const float* __restrict__ x,
                                                const float* __restrict__ W,
                                                const float* __restrict__ bias,
                                                float* __restrict__ ep) {
    __shared__ float red[SPLITH][ROWS_PB][31];   // pitch 31: conflict-free

    int tid = threadIdx.x;
    int wv = __builtin_amdgcn_readfirstlane(tid >> 6);   // wave id, SGPR
    int lane = tid & 63;                                 // row within block
    long row = (long)blockIdx.x * ROWS_PB + lane;

    const float* xr = x + row * HD + wv * HSL;
    const float* wr = W + (long)wv * HSL * PC;           // scalar base

    float acc[PC];
    #pragma unroll
    for (int c = 0; c < PC; c++) acc[c] = 0.f;

    for (int h = 0; h < HSL; h += 4) {
        float4 xv = *(const float4*)(xr + h);
        #pragma unroll
        for (int j = 0; j < 4; j++) {
            float xs = (j == 0) ? xv.x : (j == 1) ? xv.y : (j == 2) ? xv.z : xv.w;
            #pragma unroll
            for (int c = 0; c < PC; c++)
                acc[c] += xs * wr[(h + j) * PC + c];     // wave-uniform -> s_load
        }
    }

    #pragma unroll
    for (int c = 0; c < PC; c++) red[wv][lane][c] = acc[c];
    __syncthreads();

    // reduce 4 partials, exp-transform, store: 64 rows x 30 cols = 1920 vals
    for (int idx = tid; idx < ROWS_PB * PC; idx += 256) {
        int r = idx / PC, c = idx % PC;
        float s = red[0][r][c] + red[1][r][c] + red[2][r][c] + red[3][r][c];
        float e = __expf(s + bias[c]);
        float val = (c >= 10 && c < 20) ? (-e * LOG2E) : e;
        ep[((long)blockIdx.x * ROWS_PB + r) * PP + c] = val;
    }
}

// -------- kernel 2: fused gaussian window + btu,bua->bta einsum
#define TT 32     // t-tile per block
#define UC 40     // u chunk
#define NCHUNK 15 // 600/40
#define NTHR 320  // 5 waves

__global__ __launch_bounds__(NTHR) void k_main(const float* __restrict__ ep,
                                               const float* __restrict__ cs,
                                               float* __restrict__ out) {
    __shared__ float params_l[TT * 33];   // pitch 33: kill bank conflicts
    __shared__ float cs_l[UC * AD];       // [u][a] pitch 80
    __shared__ float phi_l[UC * 33];      // [u][t] pitch 33

    int tid = threadIdx.x;
    int b = blockIdx.y;
    int t0 = blockIdx.x * TT;
    long r0 = (long)b * TD + t0;

    // ---- stage params for this block's 32 t's
    for (int idx = tid; idx < TT * PP; idx += NTHR) {
        int tt_ = idx >> 5, j = idx & 31;
        params_l[tt_ * 33 + j] = ep[r0 * PP + idx];
    }
    __syncthreads();

    // ---- phi role: thread owns t = tt (tid&31), u-slice sub (tid>>5, 0..9)
    int tt = tid & 31;
    int sub = tid >> 5;
    float pa[KG], pnb[KG], pk[KG];
    #pragma unroll
    for (int q = 0; q < KG; q++) {
        pa[q]  = params_l[tt * 33 + q];
        pnb[q] = params_l[tt * 33 + 10 + q];
        pk[q]  = params_l[tt * 33 + 20 + q];
    }

    // ---- einsum role: thread owns t-pair ty*2, a-quad tx*4
    int tx = tid % 20;   // 0..19
    int ty = tid / 20;   // 0..15
    float4 acc0 = {0.f, 0.f, 0.f, 0.f};
    float4 acc1 = {0.f, 0.f, 0.f, 0.f};

    const float* csb = cs + (long)b * UD * AD;

    for (int ch = 0; ch < NCHUNK; ch++) {
        int u0 = ch * UC;
        __syncthreads();   // protect cs_l/phi_l from previous einsum readers

        // stage char_seq chunk: contiguous UC*AD floats, fully coalesced
        for (int idx = tid; idx < UC * AD; idx += NTHR) {
            cs_l[idx] = csb[u0 * AD + idx];
        }

        // compute phi for my t, my 4 u's
        #pragma unroll
        for (int i = 0; i < 4; i++) {
            int uu = sub * 4 + i;
            float uf = (float)(u0 + uu);
            float s = 0.f;
            #pragma unroll
            for (int q = 0; q < KG; q++) {
                float d = uf - pk[q];
                s += pa[q] * EXP2F(pnb[q] * d * d);
            }
            phi_l[uu * 33 + tt] = s;
        }
        __syncthreads();

        // einsum accumulate: out[t][a] += phi[t][u] * cs[u][a]
        #pragma unroll 8
        for (int uu = 0; uu < UC; uu++) {
            float p0 = phi_l[uu * 33 + ty * 2];
            float p1 = phi_l[uu * 33 + ty * 2 + 1];
            float4 c4 = *(const float4*)&cs_l[uu * AD + tx * 4];
            acc0.x += p0 * c4.x; acc0.y += p0 * c4.y;
            acc0.z += p0 * c4.z; acc0.w += p0 * c4.w;
            acc1.x += p1 * c4.x; acc1.y += p1 * c4.y;
            acc1.z += p1 * c4.z; acc1.w += p1 * c4.w;
        }
    }

    // ---- store 2 t-rows x 4 a's
    long t = r0 + ty * 2;
    *(float4*)(out + t * AD + tx * 4) = acc0;
    *(float4*)(out + (t + 1) * AD + tx * 4) = acc1;
}

extern "C" void kernel_launch(void* const* d_in, const int* in_sizes, int n_in,
                              void* d_out, int out_size, void* d_ws, size_t ws_size,
                              hipStream_t stream) {
    const float* lstm = (const float*)d_in[0];   // [16,1024,512]
    const float* cs   = (const float*)d_in[1];   // [16,600,80]
    const float* W    = (const float*)d_in[2];   // [512,30]
    const float* bias = (const float*)d_in[3];   // [30]
    float* out = (float*)d_out;                  // [16,1024,80]

    float* ep = (float*)d_ws;                    // 16384*32 floats = 2 MB

    k_params<<<(BB * TD) / ROWS_PB, 256, 0, stream>>>(lstm, W, bias, ep);
    dim3 grid(TD / TT, BB);
    k_main<<<grid, NTHR, 0, stream>>>(ep, cs, out);
}

// Round 3
// 104.809 us; speedup vs baseline: 2.5993x; 1.6294x over previous
//
#include <hip/hip_runtime.h>
#include <math.h>

#define BB 16
#define TD 1024
#define HD 512
#define UD 600
#define AD 80
#define KG 10
#define PC 30      // 3*K
#define PP 32      // padded param cols

#define LOG2E 1.4426950408889634f

#if __has_builtin(__builtin_amdgcn_exp2f)
#define EXP2F(x) __builtin_amdgcn_exp2f(x)
#else
#define EXP2F(x) exp2f(x)
#endif

// ======== kernel 1: params GEMM + exp + transform ========
// [16384 x 512] @ [512 x 30]. 512 blocks x 256 thr: 32 rows x 8 h-slices.
// Thread (r = tid>>3, s = tid&7): row = blk*32+r, h in [64s, 64s+64).
// W broadcast from LDS, slice-interleaved layout lds_w[hw][s][36]:
//   bank(s,c) = (36s+c)%32 = 4s+c -> 8 slices x float4 tile all 32 banks.
// Two phases of 32 h each so LDS stays at 36.9 KB (4 blocks/CU).
// Cross-slice reduce: __shfl_xor over the 8-lane group (s lives in lane&7).
// ep[row][32]: c 0..9 a=exp(p); 10..19 nb=-exp(p)*log2e; 20..29 k=exp(p)
#define RPB 32     // rows per block
#define WPITCH 36

__global__ __launch_bounds__(256) void k_params(const float* __restrict__ x,
                                                const float* __restrict__ W,
                                                const float* __restrict__ bias,
                                                float* __restrict__ ep) {
    __shared__ float lds_w[32 * 8 * WPITCH];   // 36864 B

    int tid = threadIdx.x;
    int r = tid >> 3;          // 0..31 row in block
    int s = tid & 7;           // 0..7  h-slice
    long row = (long)blockIdx.x * RPB + r;
    const float* xr = x + row * HD + s * 64;

    float acc[PC];
    #pragma unroll
    for (int c = 0; c < PC; c++) acc[c] = 0.f;

    for (int p = 0; p < 2; p++) {
        // stage W rows whose (h mod 64) is in [32p, 32p+32): 256 rows x 30
        __syncthreads();
        for (int idx = tid; idx < 256 * PC; idx += 256) {
            int wr_ = idx / PC, c = idx % PC;
            int s_ = wr_ >> 5, hw = wr_ & 31;
            int gh = s_ * 64 + p * 32 + hw;
            lds_w[(hw * 8 + s_) * WPITCH + c] = W[gh * PC + c];
        }
        __syncthreads();

        #pragma unroll
        for (int hb = 0; hb < 32; hb += 4) {
            float4 xv = *(const float4*)(xr + p * 32 + hb);
            #pragma unroll
            for (int j = 0; j < 4; j++) {
                float xs = (j == 0) ? xv.x : (j == 1) ? xv.y : (j == 2) ? xv.z : xv.w;
                const float* wrow = &lds_w[((hb + j) * 8 + s) * WPITCH];
                float4 w0 = *(const float4*)(wrow + 0);
                float4 w1 = *(const float4*)(wrow + 4);
                float4 w2 = *(const float4*)(wrow + 8);
                float4 w3 = *(const float4*)(wrow + 12);
                float4 w4 = *(const float4*)(wrow + 16);
                float4 w5 = *(const float4*)(wrow + 20);
                float4 w6 = *(const float4*)(wrow + 24);
                float2 w7 = *(const float2*)(wrow + 28);
                acc[0]  += xs * w0.x; acc[1]  += xs * w0.y; acc[2]  += xs * w0.z; acc[3]  += xs * w0.w;
                acc[4]  += xs * w1.x; acc[5]  += xs * w1.y; acc[6]  += xs * w1.z; acc[7]  += xs * w1.w;
                acc[8]  += xs * w2.x; acc[9]  += xs * w2.y; acc[10] += xs * w2.z; acc[11] += xs * w2.w;
                acc[12] += xs * w3.x; acc[13] += xs * w3.y; acc[14] += xs * w3.z; acc[15] += xs * w3.w;
                acc[16] += xs * w4.x; acc[17] += xs * w4.y; acc[18] += xs * w4.z; acc[19] += xs * w4.w;
                acc[20] += xs * w5.x; acc[21] += xs * w5.y; acc[22] += xs * w5.z; acc[23] += xs * w5.w;
                acc[24] += xs * w6.x; acc[25] += xs * w6.y; acc[26] += xs * w6.z; acc[27] += xs * w6.w;
                acc[28] += xs * w7.x; acc[29] += xs * w7.y;
            }
        }
    }

    // reduce over the 8 slices (lanes differing in bits 0..2)
    #pragma unroll
    for (int c = 0; c < PC; c++) {
        float v = acc[c];
        v += __shfl_xor(v, 1);
        v += __shfl_xor(v, 2);
        v += __shfl_xor(v, 4);
        acc[c] = v;
    }

    if (s == 0) {
        float o[PC];
        #pragma unroll
        for (int c = 0; c < PC; c++) {
            float e = __expf(acc[c] + bias[c]);
            o[c] = (c >= 10 && c < 20) ? (-e * LOG2E) : e;
        }
        float* dst = ep + row * PP;
        *(float4*)(dst + 0)  = make_float4(o[0],  o[1],  o[2],  o[3]);
        *(float4*)(dst + 4)  = make_float4(o[4],  o[5],  o[6],  o[7]);
        *(float4*)(dst + 8)  = make_float4(o[8],  o[9],  o[10], o[11]);
        *(float4*)(dst + 12) = make_float4(o[12], o[13], o[14], o[15]);
        *(float4*)(dst + 16) = make_float4(o[16], o[17], o[18], o[19]);
        *(float4*)(dst + 20) = make_float4(o[20], o[21], o[22], o[23]);
        *(float4*)(dst + 24) = make_float4(o[24], o[25], o[26], o[27]);
        *(float2*)(dst + 28) = make_float2(o[28], o[29]);
    }
}

// ======== kernel 2: fused gaussian window + btu,bua->bta einsum ========
// Dynamic u-range: terms with a*exp2(nb*d^2) < a*2^-46 are skipped; per block
// bound from actual params => exact for any input up to <1e-8 absolute.
#define TT 32     // t-tile per block
#define UC 40     // u chunk
#define NCHUNK 15 // 600/40
#define NTHR 320  // 5 waves

__global__ __launch_bounds__(NTHR) void k_main(const float* __restrict__ ep,
                                               const float* __restrict__ cs,
                                               float* __restrict__ out) {
    __shared__ float params_l[TT * 33];   // pitch 33: kill bank conflicts
    __shared__ float cs_l[UC * AD];       // [u][a] pitch 80
    __shared__ float phi_l[UC * 33];      // [u][t] pitch 33
    __shared__ float blo[TT], bhi[TT];

    int tid = threadIdx.x;
    int b = blockIdx.y;
    int t0 = blockIdx.x * TT;
    long r0 = (long)b * TD + t0;

    // ---- stage params for this block's 32 t's
    for (int idx = tid; idx < TT * PP; idx += NTHR) {
        int tt_ = idx >> 5, j = idx & 31;
        params_l[tt_ * 33 + j] = ep[r0 * PP + idx];
    }
    __syncthreads();

    // ---- phi role: thread owns t = tt (tid&31), u-slice sub (tid>>5, 0..9)
    int tt = tid & 31;
    int sub = tid >> 5;
    float pa[KG], pnb[KG], pk[KG];
    #pragma unroll
    for (int q = 0; q < KG; q++) {
        pa[q]  = params_l[tt * 33 + q];
        pnb[q] = params_l[tt * 33 + 10 + q];
        pk[q]  = params_l[tt * 33 + 20 + q];
    }

    // ---- dynamic contributing u-range for this t (threads tid<32 publish)
    {
        float lo = 1e30f, hi = -1e30f;
        #pragma unroll
        for (int q = 0; q < KG; q++) {
            float bits = 46.f + fmaxf(0.f, __log2f(pa[q]));
            float w = __fsqrt_rn(bits / (-pnb[q]));   // pnb<0 strictly
            lo = fminf(lo, pk[q] - w);
            hi = fmaxf(hi, pk[q] + w);
        }
        if (tid < TT) { blo[tid] = lo; bhi[tid] = hi; }
    }
    __syncthreads();
    float lo_m = 1e30f, hi_m = -1e30f;
    #pragma unroll 8
    for (int i = 0; i < TT; i++) {
        lo_m = fminf(lo_m, blo[i]);
        hi_m = fmaxf(hi_m, bhi[i]);
    }
    lo_m = fmaxf(lo_m, 0.f);
    hi_m = fminf(hi_m, (float)(UD - 1));
    int ch_lo = (int)lo_m / UC;
    int ch_hi = (int)fmaxf(hi_m, 0.f) / UC;
    if (ch_hi >= NCHUNK) ch_hi = NCHUNK - 1;
    if (ch_lo > ch_hi) ch_lo = ch_hi;

    // ---- einsum role: thread owns t-pair ty*2, a-quad tx*4
    int tx = tid % 20;   // 0..19
    int ty = tid / 20;   // 0..15
    float4 acc0 = {0.f, 0.f, 0.f, 0.f};
    float4 acc1 = {0.f, 0.f, 0.f, 0.f};

    const float* csb = cs + (long)b * UD * AD;

    for (int ch = ch_lo; ch <= ch_hi; ch++) {
        int u0 = ch * UC;
        __syncthreads();   // protect cs_l/phi_l from previous einsum readers

        // stage char_seq chunk: contiguous UC*AD floats, fully coalesced
        for (int idx = tid; idx < UC * AD; idx += NTHR) {
            cs_l[idx] = csb[u0 * AD + idx];
        }

        // compute phi for my t, my 4 u's
        #pragma unroll
        for (int i = 0; i < 4; i++) {
            int uu = sub * 4 + i;
            float uf = (float)(u0 + uu);
            float ss = 0.f;
            #pragma unroll
            for (int q = 0; q < KG; q++) {
                float d = uf - pk[q];
                ss += pa[q] * EXP2F(pnb[q] * d * d);
            }
            phi_l[uu * 33 + tt] = ss;
        }
        __syncthreads();

        // einsum accumulate: out[t][a] += phi[t][u] * cs[u][a]
        #pragma unroll 8
        for (int uu = 0; uu < UC; uu++) {
            float p0 = phi_l[uu * 33 + ty * 2];
            float p1 = phi_l[uu * 33 + ty * 2 + 1];
            float4 c4 = *(const float4*)&cs_l[uu * AD + tx * 4];
            acc0.x += p0 * c4.x; acc0.y += p0 * c4.y;
            acc0.z += p0 * c4.z; acc0.w += p0 * c4.w;
            acc1.x += p1 * c4.x; acc1.y += p1 * c4.y;
            acc1.z += p1 * c4.z; acc1.w += p1 * c4.w;
        }
    }

    // ---- store 2 t-rows x 4 a's
    long t = r0 + ty * 2;
    *(float4*)(out + t * AD + tx * 4) = acc0;
    *(float4*)(out + (t + 1) * AD + tx * 4) = acc1;
}

extern "C" void kernel_launch(void* const* d_in, const int* in_sizes, int n_in,
                              void* d_out, int out_size, void* d_ws, size_t ws_size,
                              hipStream_t stream) {
    const float* lstm = (const float*)d_in[0];   // [16,1024,512]
    const float* cs   = (const float*)d_in[1];   // [16,600,80]
    const float* W    = (const float*)d_in[2];   // [512,30]
    const float* bias = (const float*)d_in[3];   // [30]
    float* out = (float*)d_out;                  // [16,1024,80]

    float* ep = (float*)d_ws;                    // 16384*32 floats = 2 MB

    k_params<<<(BB * TD) / RPB, 256, 0, stream>>>(lstm, W, bias, ep);
    dim3 grid(TD / TT, BB);
    k_main<<<grid, NTHR, 0, stream>>>(ep, cs, out);
}